// Round 1
// baseline (1061.656 us; speedup 1.0000x reference)
//
#include <hip/hip_runtime.h>
#include <math.h>

// Problem constants (from reference)
#define N_NODES 69
#define NP      72        // padded node count (zeros in rows/cols 69..71)
#define BT_TOTAL 32768    // B*T = 32*1024
#define F_IN    8
#define H1      32
#define H2      16

#define TB      8         // bt-instances per block
#define BLOCK   256

// ---------------------------------------------------------------------------
// Kernel 1: adj_n = D^-1/2 (A + I) D^-1/2, written zero-padded to [NP][NP]
// ---------------------------------------------------------------------------
__global__ void adj_norm_kernel(const float* __restrict__ adj,
                                float* __restrict__ adjn) {
    __shared__ float dinv[N_NODES];
    const int tid = threadIdx.x;
    if (tid < N_NODES) {
        float s = 1.0f;  // +I diagonal contribution
        for (int j = 0; j < N_NODES; ++j) s += adj[tid * N_NODES + j];
        dinv[tid] = rsqrtf(s);
    }
    __syncthreads();
    for (int idx = tid; idx < NP * NP; idx += blockDim.x) {
        const int i = idx / NP, j = idx % NP;
        float v = 0.0f;
        if (i < N_NODES && j < N_NODES) {
            float a = adj[i * N_NODES + j] + (i == j ? 1.0f : 0.0f);
            v = a * dinv[i] * dinv[j];
        }
        adjn[idx] = v;
    }
}

// ---------------------------------------------------------------------------
// Kernel 2: per (b,t): out = sigmoid( adj_n @ ( relu(adj_n @ X @ W1) @ W2 ) )
// Layer 2 reordered as adj_n @ (H @ W2): 223k vs 375k FLOP per bt.
// One block processes TB consecutive bt's. adj_n is symmetric, so
// adj_s[m*NP + n] == adj[n][m]; lanes with consecutive n read contiguous LDS.
// ---------------------------------------------------------------------------
__global__ __launch_bounds__(BLOCK, 2) void gcn_kernel(
    const float* __restrict__ x,     // [N][BT][F_IN]
    const float* __restrict__ adjn,  // [NP][NP] padded
    const float* __restrict__ W1,    // [F_IN][H1]
    const float* __restrict__ W2,    // [H1][H2]
    float* __restrict__ out)         // [BT][N_NODES][H2]
{
    __shared__ float adj_s[NP * NP];                 // 20736 B
    __shared__ float X_s[TB * NP * F_IN];            // 18432 B  [bt][m][f]
    // Z in j4-plane layout: Z_s[((bt*4 + j4)*NP + m)*4 + jj]  -> b128 writes
    // from consecutive-n lanes land on consecutive 16B chunks (conflict-free)
    __shared__ float Z_s[TB * 4 * NP * 4];           // 36864 B
    __shared__ float W1_s[F_IN * H1];                // 1024 B
    __shared__ float W2_s[H1 * H2];                  // 2048 B
    // total ~79.1 KB -> 2 blocks/CU

    const int tid = threadIdx.x;
    const int bt0 = blockIdx.x * TB;

    // ---- stage adj_n (1296 float4) ----
    for (int i = tid; i < (NP * NP) / 4; i += BLOCK)
        ((float4*)adj_s)[i] = ((const float4*)adjn)[i];

    // ---- stage W1 (64 float4) + W2 (128 float4) ----
    for (int i = tid; i < (F_IN * H1 + H1 * H2) / 4; i += BLOCK) {
        if (i < (F_IN * H1) / 4)
            ((float4*)W1_s)[i] = ((const float4*)W1)[i];
        else
            ((float4*)W2_s)[i - (F_IN * H1) / 4] =
                ((const float4*)W2)[i - (F_IN * H1) / 4];
    }

    // ---- stage X: X_s[bt][m][f] = x[(m*BT + bt0+bt)*F + f]; rows >=69 zero ----
    // 1152 float4s; per m the TB*F_IN=64 floats are contiguous in global (256B).
    for (int i = tid; i < NP * TB * (F_IN / 4); i += BLOCK) {
        const int m  = i / (TB * 2);
        const int r  = i % (TB * 2);
        const int bt = r >> 1;
        const int f4 = r & 1;
        float4 v = make_float4(0.f, 0.f, 0.f, 0.f);
        if (m < N_NODES)
            v = ((const float4*)x)[(size_t)(m * BT_TOTAL + bt0 + bt) * 2 + f4];
        ((float4*)X_s)[(bt * NP + m) * 2 + f4] = v;
    }
    __syncthreads();

    // ---- fused phase B+C+D: thread owns (bt, n); Y1 -> H -> Z row in regs ----
    for (int r = tid; r < TB * NP; r += BLOCK) {
        const int n  = r % NP;     // fastest -> contiguous adj_s reads per lane
        const int bt = r / NP;

        // Y1[n][0:8] = sum_m adj[n][m] * X[m][0:8]   (adj[n][m] = adj_s[m*NP+n])
        float y[F_IN];
#pragma unroll
        for (int f = 0; f < F_IN; ++f) y[f] = 0.f;
        for (int m = 0; m < NP; ++m) {
            const float a = adj_s[m * NP + n];
            const float4 x0 = ((const float4*)X_s)[(bt * NP + m) * 2 + 0];
            const float4 x1 = ((const float4*)X_s)[(bt * NP + m) * 2 + 1];
            y[0] += a * x0.x; y[1] += a * x0.y; y[2] += a * x0.z; y[3] += a * x0.w;
            y[4] += a * x1.x; y[5] += a * x1.y; y[6] += a * x1.z; y[7] += a * x1.w;
        }

        // H[n][0:32] = relu(Y1 @ W1)
        float h[H1];
#pragma unroll
        for (int i = 0; i < H1; ++i) h[i] = 0.f;
#pragma unroll
        for (int f = 0; f < F_IN; ++f) {
            const float yf = y[f];
#pragma unroll
            for (int h4 = 0; h4 < H1 / 4; ++h4) {
                const float4 w = ((const float4*)W1_s)[f * (H1 / 4) + h4];
                h[h4 * 4 + 0] += yf * w.x;
                h[h4 * 4 + 1] += yf * w.y;
                h[h4 * 4 + 2] += yf * w.z;
                h[h4 * 4 + 3] += yf * w.w;
            }
        }
#pragma unroll
        for (int i = 0; i < H1; ++i) h[i] = fmaxf(h[i], 0.f);

        // Z[n][0:16] = H @ W2
        float z[H2];
#pragma unroll
        for (int i = 0; i < H2; ++i) z[i] = 0.f;
#pragma unroll
        for (int hh = 0; hh < H1; ++hh) {
            const float hv = h[hh];
#pragma unroll
            for (int j4 = 0; j4 < H2 / 4; ++j4) {
                const float4 w = ((const float4*)W2_s)[hh * (H2 / 4) + j4];
                z[j4 * 4 + 0] += hv * w.x;
                z[j4 * 4 + 1] += hv * w.y;
                z[j4 * 4 + 2] += hv * w.z;
                z[j4 * 4 + 3] += hv * w.w;
            }
        }

        // write Z row to LDS planes
#pragma unroll
        for (int j4 = 0; j4 < 4; ++j4) {
            ((float4*)Z_s)[(bt * 4 + j4) * NP + n] =
                make_float4(z[j4 * 4 + 0], z[j4 * 4 + 1],
                            z[j4 * 4 + 2], z[j4 * 4 + 3]);
        }
    }
    __syncthreads();

    // ---- phase E: out[bt][n][:] = sigmoid( sum_m adj[n][m] * Z[m][:] ) ----
    for (int r = tid; r < TB * NP; r += BLOCK) {
        const int n  = r % NP;
        const int bt = r / NP;
        if (n >= N_NODES) continue;   // padded rows produce no output

        float acc[H2];
#pragma unroll
        for (int i = 0; i < H2; ++i) acc[i] = 0.f;
        for (int m = 0; m < NP; ++m) {
            const float a = adj_s[m * NP + n];
            const float4 z0 = ((const float4*)Z_s)[(bt * 4 + 0) * NP + m];
            const float4 z1 = ((const float4*)Z_s)[(bt * 4 + 1) * NP + m];
            const float4 z2 = ((const float4*)Z_s)[(bt * 4 + 2) * NP + m];
            const float4 z3 = ((const float4*)Z_s)[(bt * 4 + 3) * NP + m];
            acc[0]  += a * z0.x; acc[1]  += a * z0.y; acc[2]  += a * z0.z; acc[3]  += a * z0.w;
            acc[4]  += a * z1.x; acc[5]  += a * z1.y; acc[6]  += a * z1.z; acc[7]  += a * z1.w;
            acc[8]  += a * z2.x; acc[9]  += a * z2.y; acc[10] += a * z2.z; acc[11] += a * z2.w;
            acc[12] += a * z3.x; acc[13] += a * z3.y; acc[14] += a * z3.z; acc[15] += a * z3.w;
        }
#pragma unroll
        for (int j4 = 0; j4 < 4; ++j4) {
            float4 o;
            o.x = 1.0f / (1.0f + __expf(-acc[j4 * 4 + 0]));
            o.y = 1.0f / (1.0f + __expf(-acc[j4 * 4 + 1]));
            o.z = 1.0f / (1.0f + __expf(-acc[j4 * 4 + 2]));
            o.w = 1.0f / (1.0f + __expf(-acc[j4 * 4 + 3]));
            ((float4*)out)[(size_t)((bt0 + bt) * N_NODES + n) * 4 + j4] = o;
        }
    }
}

// ---------------------------------------------------------------------------
extern "C" void kernel_launch(void* const* d_in, const int* in_sizes, int n_in,
                              void* d_out, int out_size, void* d_ws, size_t ws_size,
                              hipStream_t stream) {
    const float* x   = (const float*)d_in[0];  // [69][32768][8]
    const float* adj = (const float*)d_in[1];  // [69][69]
    const float* W1  = (const float*)d_in[2];  // [8][32]
    const float* W2  = (const float*)d_in[3];  // [32][16]
    float* out  = (float*)d_out;               // [32768][69][16]
    float* adjn = (float*)d_ws;                // [72][72] scratch (20.7 KB)

    adj_norm_kernel<<<1, BLOCK, 0, stream>>>(adj, adjn);
    gcn_kernel<<<BT_TOTAL / TB, BLOCK, 0, stream>>>(x, adjn, W1, W2, out);
}

// Round 2
// 484.188 us; speedup vs baseline: 2.1927x; 2.1927x over previous
//
#include <hip/hip_runtime.h>
#include <math.h>

// Problem constants
#define N_NODES 69
#define MP      80        // padded M (adjacency rows), 5 tiles of 16
#define KP      96        // padded K (adjacency cols), 3 tiles of 32
#define BT_TOTAL 32768
#define F_IN    8
#define H1      32
#define H2      16

#define TBT     8         // bt-instances per block
#define BLOCK   256       // 4 waves

// LDS pitches (u16 units for bf16 planes, fp32 units for Y1)
#define XPITCH  68        // X planes: cols 64, pad 4 (u16)
#define ZPITCH  136       // Z plane: cols 128, pad 8 (u16)
#define YPITCH  68        // Y1: cols 64, pad 4 (fp32)

typedef __attribute__((ext_vector_type(8))) short bf16x8;   // 8 bf16 in 4 VGPRs
typedef __attribute__((ext_vector_type(4))) float f32x4;

__device__ __forceinline__ unsigned short f2bf(float f) {
    unsigned u = __float_as_uint(f);
    return (unsigned short)((u + 0x7FFFu + ((u >> 16) & 1u)) >> 16);
}
__device__ __forceinline__ float bf2f(unsigned short h) {
    return __uint_as_float(((unsigned)h) << 16);
}

// ---------------------------------------------------------------------------
// Kernel 1: adjn = D^-1/2 (A+I) D^-1/2, split into bf16 hi+lo planes,
// zero-padded to [MP][KP].
// ---------------------------------------------------------------------------
__global__ void adj_norm_kernel(const float* __restrict__ adj,
                                unsigned short* __restrict__ adjh,
                                unsigned short* __restrict__ adjl) {
    __shared__ float dinv[N_NODES];
    const int tid = threadIdx.x;
    if (tid < N_NODES) {
        float s = 1.0f;
        for (int j = 0; j < N_NODES; ++j) s += adj[tid * N_NODES + j];
        dinv[tid] = rsqrtf(s);
    }
    __syncthreads();
    for (int idx = tid; idx < MP * KP; idx += blockDim.x) {
        const int n = idx / KP, m = idx % KP;
        float v = 0.0f;
        if (n < N_NODES && m < N_NODES) {
            float a = adj[n * N_NODES + m] + (n == m ? 1.0f : 0.0f);
            v = a * dinv[n] * dinv[m];
        }
        unsigned short h = f2bf(v);
        adjh[idx] = h;
        adjl[idx] = f2bf(v - bf2f(h));
    }
}

// ---------------------------------------------------------------------------
// Kernel 2: fused GCN. Phase1: Y1 = adjn@X (MFMA, split-bf16).
// Phase2: Z = relu(Y1@W1)@W2 (VALU fp32, W via scalar loads).
// Phase3: out = sigmoid(adjn@Z) (MFMA bf16).
// ---------------------------------------------------------------------------
__global__ __launch_bounds__(BLOCK, 3) void gcn_kernel(
    const float* __restrict__ x,           // [69][BT][8]
    const unsigned short* __restrict__ adjh,  // [80][96] bf16 hi
    const unsigned short* __restrict__ adjl,  // [80][96] bf16 lo
    const float* __restrict__ W1,          // [8][32]
    const float* __restrict__ W2,          // [32][16]
    float* __restrict__ out)               // [BT][69][16]
{
    // U_s: phase1 = X_hi [96][68] @ 0, X_lo [96][68] @ 96*68;  phase2/3 = Z [96][136]
    __shared__ unsigned short U_s[KP * ZPITCH];     // 26112 B
    __shared__ float Y1_s[MP * YPITCH];             // 21760 B
    // total 47872 B -> 3 blocks/CU

    const int tid  = threadIdx.x;
    const int lane = tid & 63;
    const int wv   = tid >> 6;
    const int quad = lane >> 4;
    const int l16  = lane & 15;
    const int bt0  = blockIdx.x * TBT;

    unsigned short* Xhi = U_s;
    unsigned short* Xlo = U_s + KP * XPITCH;

    // ---- stage X -> bf16 hi/lo planes, row-major [m][bt*8+f] ----
    // 69 rows x 16 float4 = 1104 loads; 64 contiguous floats per row.
    for (int i = tid; i < N_NODES * 16; i += BLOCK) {
        const int m = i >> 4, c4 = i & 15;
        const float4 v = ((const float4*)x)[(size_t)m * (BT_TOTAL * 2) + bt0 * 2 + c4];
        unsigned short h0 = f2bf(v.x), h1 = f2bf(v.y), h2 = f2bf(v.z), h3 = f2bf(v.w);
        uint2 hi2 = make_uint2((unsigned)h0 | ((unsigned)h1 << 16),
                               (unsigned)h2 | ((unsigned)h3 << 16));
        unsigned short g0 = f2bf(v.x - bf2f(h0)), g1 = f2bf(v.y - bf2f(h1));
        unsigned short g2 = f2bf(v.z - bf2f(h2)), g3 = f2bf(v.w - bf2f(h3));
        uint2 lo2 = make_uint2((unsigned)g0 | ((unsigned)g1 << 16),
                               (unsigned)g2 | ((unsigned)g3 << 16));
        *(uint2*)((char*)Xhi + 2 * (m * XPITCH + 4 * c4)) = hi2;
        *(uint2*)((char*)Xlo + 2 * (m * XPITCH + 4 * c4)) = lo2;
    }
    // zero pad rows 69..95 of both planes (34 dwords per row per plane)
    for (int i = tid; i < 27 * 34; i += BLOCK) {
        const int row = N_NODES + i / 34, w = i % 34;
        ((unsigned*)Xhi)[row * 34 + w] = 0u;
        ((unsigned*)Xlo)[row * 34 + w] = 0u;
    }
    __syncthreads();

    // ---- phase 1: Y1[n][col] = adjn @ X, cols = 64 (8 bt x 8 f) ----
    {
        const int ct = wv;               // one 16-col tile per wave
        const int col = ct * 16 + l16;
        bf16x8 bh[3], bl[3];
#pragma unroll
        for (int kt = 0; kt < 3; ++kt) {
            const int k0 = kt * 32 + quad * 8;
#pragma unroll
            for (int j = 0; j < 8; ++j) {
                bh[kt][j] = (short)Xhi[(k0 + j) * XPITCH + col];
                bl[kt][j] = (short)Xlo[(k0 + j) * XPITCH + col];
            }
        }
#pragma unroll
        for (int mt = 0; mt < 5; ++mt) {
            f32x4 acc = {0.f, 0.f, 0.f, 0.f};
#pragma unroll
            for (int kt = 0; kt < 3; ++kt) {
                const int aoff = (mt * 16 + l16) * KP + kt * 32 + quad * 8;
                const bf16x8 ah = *(const bf16x8*)(adjh + aoff);
                const bf16x8 al = *(const bf16x8*)(adjl + aoff);
                acc = __builtin_amdgcn_mfma_f32_16x16x32_bf16(ah, bh[kt], acc, 0, 0, 0);
                acc = __builtin_amdgcn_mfma_f32_16x16x32_bf16(ah, bl[kt], acc, 0, 0, 0);
                acc = __builtin_amdgcn_mfma_f32_16x16x32_bf16(al, bh[kt], acc, 0, 0, 0);
            }
#pragma unroll
            for (int reg = 0; reg < 4; ++reg) {
                const int row = mt * 16 + quad * 4 + reg;
                Y1_s[row * YPITCH + ct * 16 + l16] = acc[reg];
            }
        }
    }
    __syncthreads();

    // ---- phase 2: per (n,bt) row: H = relu(Y1@W1); Z = H@W2 -> bf16 LDS ----
    // W1/W2 read from GLOBAL with wave-uniform indices -> scalar s_load path.
    for (int r = tid; r < N_NODES * TBT; r += BLOCK) {
        const int bt = r & 7, n = r >> 3;
        const float4 y0 = *(const float4*)&Y1_s[n * YPITCH + bt * 8];
        const float4 y1 = *(const float4*)&Y1_s[n * YPITCH + bt * 8 + 4];
        const float yv[8] = {y0.x, y0.y, y0.z, y0.w, y1.x, y1.y, y1.z, y1.w};

        float h[H1];
#pragma unroll
        for (int j = 0; j < H1; ++j) h[j] = 0.f;
#pragma unroll
        for (int f = 0; f < F_IN; ++f) {
            const float yf = yv[f];
#pragma unroll
            for (int j = 0; j < H1; ++j) h[j] = fmaf(yf, W1[f * H1 + j], h[j]);
        }
#pragma unroll
        for (int j = 0; j < H1; ++j) h[j] = fmaxf(h[j], 0.f);

        float z[H2];
#pragma unroll
        for (int j = 0; j < H2; ++j) z[j] = 0.f;
#pragma unroll
        for (int hh = 0; hh < H1; ++hh) {
            const float hv = h[hh];
#pragma unroll
            for (int j = 0; j < H2; ++j) z[j] = fmaf(hv, W2[hh * H2 + j], z[j]);
        }

        unsigned zp[8];
#pragma unroll
        for (int j = 0; j < 8; ++j)
            zp[j] = (unsigned)f2bf(z[2 * j]) | ((unsigned)f2bf(z[2 * j + 1]) << 16);
        uint4* dst = (uint4*)((char*)U_s + 2 * (n * ZPITCH + bt * 16));
        dst[0] = make_uint4(zp[0], zp[1], zp[2], zp[3]);
        dst[1] = make_uint4(zp[4], zp[5], zp[6], zp[7]);
    }
    // zero Z pad rows 69..95 (68 dwords per row)
    for (int i = tid; i < 27 * 68; i += BLOCK) {
        const int row = N_NODES + i / 68, w = i % 68;
        ((unsigned*)U_s)[row * 68 + w] = 0u;
    }
    __syncthreads();

    // ---- phase 3: out = sigmoid(adjn @ Z), cols = 128 (8 bt x 16 j) ----
#pragma unroll
    for (int c = 0; c < 2; ++c) {
        const int ct = wv * 2 + c;       // col-tile == bt (16 cols per bt)
        const int col = ct * 16 + l16;
        bf16x8 bz[3];
#pragma unroll
        for (int kt = 0; kt < 3; ++kt) {
            const int k0 = kt * 32 + quad * 8;
#pragma unroll
            for (int j = 0; j < 8; ++j)
                bz[kt][j] = (short)U_s[(k0 + j) * ZPITCH + col];
        }
#pragma unroll
        for (int mt = 0; mt < 5; ++mt) {
            f32x4 acc = {0.f, 0.f, 0.f, 0.f};
#pragma unroll
            for (int kt = 0; kt < 3; ++kt) {
                const bf16x8 ah =
                    *(const bf16x8*)(adjh + (mt * 16 + l16) * KP + kt * 32 + quad * 8);
                acc = __builtin_amdgcn_mfma_f32_16x16x32_bf16(ah, bz[kt], acc, 0, 0, 0);
            }
#pragma unroll
            for (int reg = 0; reg < 4; ++reg) {
                const int n = mt * 16 + quad * 4 + reg;
                if (n < N_NODES) {
                    const float v = 1.0f / (1.0f + __expf(-acc[reg]));
                    out[((size_t)(bt0 + ct) * N_NODES + n) * H2 + l16] = v;
                }
            }
        }
    }
}

// ---------------------------------------------------------------------------
extern "C" void kernel_launch(void* const* d_in, const int* in_sizes, int n_in,
                              void* d_out, int out_size, void* d_ws, size_t ws_size,
                              hipStream_t stream) {
    const float* x   = (const float*)d_in[0];
    const float* adj = (const float*)d_in[1];
    const float* W1  = (const float*)d_in[2];
    const float* W2  = (const float*)d_in[3];
    float* out = (float*)d_out;

    unsigned short* adjh = (unsigned short*)d_ws;                 // 80*96 u16
    unsigned short* adjl = adjh + MP * KP;                        // 80*96 u16

    adj_norm_kernel<<<1, BLOCK, 0, stream>>>(adj, adjh, adjl);
    gcn_kernel<<<BT_TOTAL / TBT, BLOCK, 0, stream>>>(x, adjh, adjl, W1, W2, out);
}

// Round 3
// 265.183 us; speedup vs baseline: 4.0035x; 1.8259x over previous
//
#include <hip/hip_runtime.h>
#include <math.h>

// Problem constants
#define N_NODES 69
#define MP      80        // padded M (adjacency rows), 5 tiles of 16
#define KP      96        // padded K (adjacency cols), 3 tiles of 32
#define BT_TOTAL 32768
#define F_IN    8
#define H1      32
#define H2      16

#define TBT     8         // bt-instances per block
#define BLOCK   256       // 4 waves

#define XPITCH  68        // X planes: 64 cols + pad (u16)
#define ZPITCH  136       // Z plane: 128 cols + pad (u16)
#define RSTRIDE 72        // rows per bt in the flattened (bt,n) space
#define RROWS   576       // 8 * 72 = 36 M-tiles of 16, 9 per wave

typedef __attribute__((ext_vector_type(8))) short bf16x8;
typedef __attribute__((ext_vector_type(4))) float f32x4;

__device__ __forceinline__ unsigned short f2bf(float f) {
    unsigned u = __float_as_uint(f);
    return (unsigned short)((u + 0x7FFFu + ((u >> 16) & 1u)) >> 16);
}
__device__ __forceinline__ float bf2f(unsigned short h) {
    return __uint_as_float(((unsigned)h) << 16);
}

// ---------------------------------------------------------------------------
// Kernel 1: adjn split into bf16 hi+lo planes [MP][KP]; pre-pack W1/W2 into
// MFMA B-fragment layout (B[k][n] held by lane = (k>>3)<<4 | n, elem j = k&7).
// ---------------------------------------------------------------------------
__global__ void setup_kernel(const float* __restrict__ adj,
                             const float* __restrict__ W1,
                             const float* __restrict__ W2,
                             unsigned short* __restrict__ adjh,
                             unsigned short* __restrict__ adjl,
                             unsigned short* __restrict__ W1p,  // [2][64][8]
                             unsigned short* __restrict__ W2p)  // [64][8]
{
    __shared__ float dinv[N_NODES];
    const int tid = threadIdx.x;
    if (tid < N_NODES) {
        float s = 1.0f;
        for (int j = 0; j < N_NODES; ++j) s += adj[tid * N_NODES + j];
        dinv[tid] = rsqrtf(s);
    }
    __syncthreads();
    for (int idx = tid; idx < MP * KP; idx += BLOCK) {
        const int n = idx / KP, m = idx % KP;
        float v = 0.0f;
        if (n < N_NODES && m < N_NODES) {
            float a = adj[n * N_NODES + m] + (n == m ? 1.0f : 0.0f);
            v = a * dinv[n] * dinv[m];
        }
        unsigned short h = f2bf(v);
        adjh[idx] = h;
        adjl[idx] = f2bf(v - bf2f(h));
    }
    // W1 B-frags for 2 N-tiles; K=8 lives entirely in quad 0 (rest zero)
    for (int i = tid; i < 2 * 64 * F_IN; i += BLOCK) {
        const int nt = i >> 9;
        const int ln = (i >> 3) & 63;
        const int j  = i & 7;
        const int q = ln >> 4, l = ln & 15;
        float v = (q == 0) ? W1[j * H1 + nt * 16 + l] : 0.0f;
        W1p[i] = f2bf(v);
    }
    // W2 B-frag; K=32 uses all quads (k = q*8 + j)
    for (int i = tid; i < 64 * F_IN; i += BLOCK) {
        const int ln = i >> 3, j = i & 7;
        const int q = ln >> 4, l = ln & 15;
        W2p[i] = f2bf(W2[(q * 8 + j) * H2 + l]);
    }
}

// ---------------------------------------------------------------------------
// Kernel 2: all three stages on MFMA.
//   P1: Y1 = adjn @ X   (split-bf16, verified layout from round 2)
//   P2: Z  = relu(Y1@W1) @ W2  (per-M-tile fused, per-wave LDS transpose)
//   P3: out = sigmoid(adjn @ Z)
// ---------------------------------------------------------------------------
__global__ __launch_bounds__(BLOCK, 4) void gcn_kernel(
    const float* __restrict__ x,              // [69][BT][8]
    const unsigned short* __restrict__ adjh,  // [80][96]
    const unsigned short* __restrict__ adjl,  // [80][96]
    const unsigned short* __restrict__ W1p,   // [2][64][8]
    const unsigned short* __restrict__ W2p,   // [64][8]
    float* __restrict__ out)                  // [BT][69][16]
{
    // U_s: phase1 = Xhi [96][68] @ 0, Xlo @ 96*68; phase2/3 = Z [96][136]
    __shared__ unsigned short U_s[KP * ZPITCH];       // 26112 B
    __shared__ unsigned short Y1_s[RROWS * F_IN];     // 9216 B  [(bt*72+n)][f] bf16
    __shared__ unsigned short Hb_s[4][16 * H1];       // 4096 B  per-wave H tile
    // total 39424 B -> 4 blocks/CU

    const int tid  = threadIdx.x;
    const int lane = tid & 63;
    const int wv   = tid >> 6;
    const int quad = lane >> 4;
    const int l16  = lane & 15;
    const int bt0  = blockIdx.x * TBT;

    unsigned short* Xhi = U_s;
    unsigned short* Xlo = U_s + KP * XPITCH;

    // ---- stage X -> bf16 hi/lo planes, row-major [m][bt*8+f] ----
    for (int i = tid; i < N_NODES * 16; i += BLOCK) {
        const int m = i >> 4, c4 = i & 15;
        const float4 v = ((const float4*)x)[(size_t)m * (BT_TOTAL * 2) + bt0 * 2 + c4];
        unsigned short h0 = f2bf(v.x), h1 = f2bf(v.y), h2 = f2bf(v.z), h3 = f2bf(v.w);
        uint2 hi2 = make_uint2((unsigned)h0 | ((unsigned)h1 << 16),
                               (unsigned)h2 | ((unsigned)h3 << 16));
        unsigned short g0 = f2bf(v.x - bf2f(h0)), g1 = f2bf(v.y - bf2f(h1));
        unsigned short g2 = f2bf(v.z - bf2f(h2)), g3 = f2bf(v.w - bf2f(h3));
        uint2 lo2 = make_uint2((unsigned)g0 | ((unsigned)g1 << 16),
                               (unsigned)g2 | ((unsigned)g3 << 16));
        *(uint2*)((char*)Xhi + 2 * (m * XPITCH + 4 * c4)) = hi2;
        *(uint2*)((char*)Xlo + 2 * (m * XPITCH + 4 * c4)) = lo2;
    }
    for (int i = tid; i < 27 * 34; i += BLOCK) {      // zero X pad rows 69..95
        const int row = N_NODES + i / 34, w = i % 34;
        ((unsigned*)Xhi)[row * 34 + w] = 0u;
        ((unsigned*)Xlo)[row * 34 + w] = 0u;
    }
    __syncthreads();

    // ---- W fragments (per-lane dwordx4, coalesced, L2-hot) ----
    const bf16x8 w1f0 = *(const bf16x8*)&W1p[lane * 8];
    const bf16x8 w1f1 = *(const bf16x8*)&W1p[(64 + lane) * 8];
    const bf16x8 w2f  = *(const bf16x8*)&W2p[lane * 8];

    // ---- phase-1 B fragments (X dead after this) ----
    const int ct  = wv;
    const int col = ct * 16 + l16;
    bf16x8 bh[3], bl[3];
#pragma unroll
    for (int kt = 0; kt < 3; ++kt) {
        const int k0 = kt * 32 + quad * 8;
#pragma unroll
        for (int j = 0; j < 8; ++j) {
            bh[kt][j] = (short)Xhi[(k0 + j) * XPITCH + col];
            bl[kt][j] = (short)Xlo[(k0 + j) * XPITCH + col];
        }
    }
    __syncthreads();   // all waves have consumed X; U_s now reusable as Z

    // ---- zero Z pad rows 69..95 (read by phase-3 B-gather) ----
    for (int i = tid; i < 27 * 64; i += BLOCK) {
        const int row = N_NODES + (i >> 6), w = i & 63;
        ((unsigned*)U_s)[row * 68 + w] = 0u;
    }

    // ---- phase 1: Y1 = adjn @ X -> Y1_s[(bt*72+n)][f] bf16 ----
    const int btc = col >> 3, fc = col & 7;
#pragma unroll
    for (int mt = 0; mt < 5; ++mt) {
        f32x4 acc = {0.f, 0.f, 0.f, 0.f};
#pragma unroll
        for (int kt = 0; kt < 3; ++kt) {
            const int aoff = (mt * 16 + l16) * KP + kt * 32 + quad * 8;
            const bf16x8 ah = *(const bf16x8*)(adjh + aoff);
            const bf16x8 al = *(const bf16x8*)(adjl + aoff);
            acc = __builtin_amdgcn_mfma_f32_16x16x32_bf16(ah, bh[kt], acc, 0, 0, 0);
            acc = __builtin_amdgcn_mfma_f32_16x16x32_bf16(ah, bl[kt], acc, 0, 0, 0);
            acc = __builtin_amdgcn_mfma_f32_16x16x32_bf16(al, bh[kt], acc, 0, 0, 0);
        }
#pragma unroll
        for (int reg = 0; reg < 4; ++reg) {
            const int n = mt * 16 + quad * 4 + reg;
            if (n < RSTRIDE)
                Y1_s[(btc * RSTRIDE + n) * F_IN + fc] = f2bf(acc[reg]);
        }
    }
    // no barrier: wave wv wrote rows [144*wv, 144*wv+144) and reads only those

    // ---- phase 2: per M-tile: H = relu(Y1@W1); Z = H@W2 ----
    unsigned short* Hb = Hb_s[wv];
#pragma unroll
    for (int mt2 = 0; mt2 < 9; ++mt2) {
        const int rb = wv * 144 + mt2 * 16;

        // A1 fragment: K=8 -> data only in quad 0, others zero
        bf16x8 af = {0, 0, 0, 0, 0, 0, 0, 0};
        if (quad == 0)
            af = *(const bf16x8*)&Y1_s[(rb + l16) * F_IN];

        f32x4 h0 = {0.f, 0.f, 0.f, 0.f};
        f32x4 h1 = {0.f, 0.f, 0.f, 0.f};
        h0 = __builtin_amdgcn_mfma_f32_16x16x32_bf16(af, w1f0, h0, 0, 0, 0);
        h1 = __builtin_amdgcn_mfma_f32_16x16x32_bf16(af, w1f1, h1, 0, 0, 0);

        // relu + pack C-layout -> Hb[m][h] (A-layout source for GEMM2)
#pragma unroll
        for (int reg = 0; reg < 4; ++reg) {
            const int row = quad * 4 + reg;
            Hb[row * H1 + l16]      = f2bf(fmaxf(h0[reg], 0.f));
            Hb[row * H1 + 16 + l16] = f2bf(fmaxf(h1[reg], 0.f));
        }
        // same-wave LDS dependency: compiler inserts lgkmcnt wait, no barrier
        const bf16x8 a2 = *(const bf16x8*)&Hb[l16 * H1 + quad * 8];

        f32x4 zk = {0.f, 0.f, 0.f, 0.f};
        zk = __builtin_amdgcn_mfma_f32_16x16x32_bf16(a2, w2f, zk, 0, 0, 0);

        // scatter Z (C-layout) -> U_s[node][bt*16 + j]
#pragma unroll
        for (int reg = 0; reg < 4; ++reg) {
            const int r  = rb + quad * 4 + reg;
            const int bt = r / RSTRIDE;
            const int n  = r - bt * RSTRIDE;
            if (n < N_NODES)
                U_s[n * ZPITCH + bt * 16 + l16] = f2bf(zk[reg]);
        }
    }
    __syncthreads();

    // ---- phase 3: out = sigmoid(adjn @ Z) ----
#pragma unroll
    for (int c = 0; c < 2; ++c) {
        const int ct3  = wv * 2 + c;          // col tile == bt
        const int col3 = ct3 * 16 + l16;
        bf16x8 bz[3];
#pragma unroll
        for (int kt = 0; kt < 3; ++kt) {
            const int k0 = kt * 32 + quad * 8;
#pragma unroll
            for (int j = 0; j < 8; ++j)
                bz[kt][j] = (short)U_s[(k0 + j) * ZPITCH + col3];
        }
#pragma unroll
        for (int mt = 0; mt < 5; ++mt) {
            f32x4 acc = {0.f, 0.f, 0.f, 0.f};
#pragma unroll
            for (int kt = 0; kt < 3; ++kt) {
                const bf16x8 ah =
                    *(const bf16x8*)(adjh + (mt * 16 + l16) * KP + kt * 32 + quad * 8);
                acc = __builtin_amdgcn_mfma_f32_16x16x32_bf16(ah, bz[kt], acc, 0, 0, 0);
            }
#pragma unroll
            for (int reg = 0; reg < 4; ++reg) {
                const int n = mt * 16 + quad * 4 + reg;
                if (n < N_NODES) {
                    const float v = 1.0f / (1.0f + __expf(-acc[reg]));
                    out[((size_t)(bt0 + ct3) * N_NODES + n) * H2 + l16] = v;
                }
            }
        }
    }
}

// ---------------------------------------------------------------------------
extern "C" void kernel_launch(void* const* d_in, const int* in_sizes, int n_in,
                              void* d_out, int out_size, void* d_ws, size_t ws_size,
                              hipStream_t stream) {
    const float* x   = (const float*)d_in[0];
    const float* adj = (const float*)d_in[1];
    const float* W1  = (const float*)d_in[2];
    const float* W2  = (const float*)d_in[3];
    float* out = (float*)d_out;

    unsigned short* adjh = (unsigned short*)d_ws;       // 80*96
    unsigned short* adjl = adjh + MP * KP;              // 80*96
    unsigned short* W1p  = adjl + MP * KP;              // 2*64*8
    unsigned short* W2p  = W1p + 2 * 64 * F_IN;         // 64*8

    setup_kernel<<<1, BLOCK, 0, stream>>>(adj, W1, W2, adjh, adjl, W1p, W2p);
    gcn_kernel<<<BT_TOTAL / TBT, BLOCK, 0, stream>>>(x, adjh, adjl, W1p, W2p, out);
}